// Round 17
// baseline (103.744 us; speedup 1.0000x reference)
//
#include <hip/hip_runtime.h>
#include <stdint.h>

typedef __bf16 bf16;
typedef __bf16 bf16x8 __attribute__((ext_vector_type(8)));
typedef float  f32x4  __attribute__((ext_vector_type(4)));
typedef unsigned short u16x4 __attribute__((ext_vector_type(4)));
typedef unsigned int   u32x4v __attribute__((ext_vector_type(4)));

#define SEQ   2048
#define DM    768
#define NH    12
#define HD    64
#define ATT_SCALE 0.125f
#define LOG2E 1.44269504f
#define LN_EPS 1e-5f

// async global->LDS, 16B per lane; LDS dest is wave-uniform base + lane*16
__device__ __forceinline__ void gload16(const void* g, void* l) {
  __builtin_amdgcn_global_load_lds((const __attribute__((address_space(1))) void*)g,
                                   (__attribute__((address_space(3))) void*)l,
                                   16, 0, 0);
}

// ---------------- prep: LN (blocks 0..4095) + weight transpose (4096..6399) -
__global__ __launch_bounds__(256) void prep_kernel(
    const float* __restrict__ x, const float* __restrict__ gamma,
    const float* __restrict__ beta, bf16* __restrict__ h,
    const float* __restrict__ Wq, const float* __restrict__ Wk,
    const float* __restrict__ Wv, const float* __restrict__ Wo,
    bf16* __restrict__ Wqkvt, bf16* __restrict__ Wot)
{
  __shared__ float smem[32*33];
  int bid = blockIdx.x, t = threadIdx.x;
  if (bid < 4096) {
    const float* xr = x + (size_t)bid*DM;
    float v0 = xr[t], v1 = xr[t+256], v2 = xr[t+512];
    float s = v0+v1+v2;
    float q = v0*v0+v1*v1+v2*v2;
    #pragma unroll
    for (int m=32;m>=1;m>>=1){ s += __shfl_xor(s,m,64); q += __shfl_xor(q,m,64); }
    float* rs = smem; float* rq = smem+8;
    int w = t>>6;
    if ((t&63)==0){ rs[w]=s; rq[w]=q; }
    __syncthreads();
    float S = rs[0]+rs[1]+rs[2]+rs[3];
    float Q = rq[0]+rq[1]+rq[2]+rq[3];
    float mean = S*(1.0f/DM);
    float var  = Q*(1.0f/DM) - mean*mean;
    float rstd = rsqrtf(var + LN_EPS);
    bf16* hr = h + (size_t)bid*DM;
    hr[t]     = (bf16)((v0-mean)*rstd*gamma[t]     + beta[t]);
    hr[t+256] = (bf16)((v1-mean)*rstd*gamma[t+256] + beta[t+256]);
    hr[t+512] = (bf16)((v2-mean)*rstd*gamma[t+512] + beta[t+512]);
  } else {
    int tb = bid - 4096;
    int z = tb/576, rem = tb%576;
    int r0 = (rem/24)*32, c0 = (rem%24)*32;
    int tx = t&31, ty = t>>5;   // (32,8)
    float (*tile)[33] = (float(*)[33])smem;
    const float* src = (z==0)?Wq:(z==1)?Wk:(z==2)?Wv:Wo;
    #pragma unroll
    for (int i=ty;i<32;i+=8) tile[i][tx] = src[(size_t)(r0+i)*DM + c0+tx];
    __syncthreads();
    bf16* dst = (z<3) ? (Wqkvt + (size_t)z*DM*DM) : Wot;
    #pragma unroll
    for (int i=ty;i<32;i+=8) dst[(size_t)(c0+i)*DM + r0+tx] = (bf16)tile[tx][i];
  }
}

// ---------------- GEMM: C = A * Bt^T — templated BK/waves/NBUF, XCD-chunked -
// 1D grid MT*NT blocks; xcd = id&7 owns MT/8 consecutive bm tiles (A-panel +
// whole B stay L2-local per XCD). NBUF-deep LDS pipeline, counted vmcnt
// (WAIT=(NBUF-2)*GL mid-loop, 0 at drain). LDS XOR-swizzle: staging
// pre-swizzles the SOURCE slot by row&SMASK (dest linear per gload_lds
// rules), frag reads XOR back. BK=64 -> conflict-free; BK=32 -> 4-way floor.
// EPI 0: QKV epilogue (Q cols scaled LOG2E; V -> V^T [b][h][d][n])
// EPI 1: out fp32 = acc + bo[col] + x[row][col]
template<int BM, int BN, int BK, int WM, int WN, int NBUF, int MT, int NT, int EPI>
__global__ __launch_bounds__(WM*WN*64) void gemm_bt(
    const bf16* __restrict__ A, const bf16* __restrict__ Bt, int K,
    bf16* __restrict__ qk, bf16* __restrict__ vt,
    float* __restrict__ out, const float* __restrict__ bo, const float* __restrict__ xres)
{
  constexpr int NW    = WM*WN;            // waves per block
  constexpr int MF    = BM/(WM*16);
  constexpr int NF    = BN/(WN*16);
  constexpr int GL    = (BM+BN)*BK/(512*NW); // gloads per wave per stage
  constexpr int RPI   = 512/BK;           // rows covered per gload16 instr
  constexpr int KKN   = BK/32;            // MFMA k-steps per tile
  constexpr int SLOTS = BK/8;             // 16B slots per row
  constexpr int SMASK = SLOTS-1;
  constexpr int PREF  = NBUF-1;           // prefetch depth
  constexpr int WAIT  = (NBUF-2)*GL;      // mid-loop counted vmcnt
  __shared__ bf16 As[NBUF][BM][BK];
  __shared__ bf16 Bs[NBUF][BN][BK];
  int tid = threadIdx.x, w = tid>>6, la = tid&63;
  int id = blockIdx.x;
  int xcd = id & 7, idx = id >> 3;        // MT*NT = 8 * (MT/8*NT), bijective
  int bm = xcd*(MT/8) + idx/NT;
  int bn = idx % NT;
  int wm = w / WN, wn = w % WN;
  int g = la>>4, li = la&15;
  int sr = la / SLOTS;                    // staging row within group
  int sc = ((la % SLOTS) ^ (sr & SMASK))*8; // pre-swizzled source col (elems)
  f32x4 acc[MF][NF] = {};
  const int KT = K/BK;

  auto stage = [&](int kt, int bb) {
    int k0 = kt*BK;
    #pragma unroll
    for (int i=0;i<BM/(RPI*NW);i++){ int r0 = (i*NW+w)*RPI;
      gload16(A + ((size_t)(bm*BM + r0 + sr))*K + k0 + sc, &As[bb][r0][0]); }
    #pragma unroll
    for (int i=0;i<BN/(RPI*NW);i++){ int r0 = (i*NW+w)*RPI;
      gload16(Bt + ((size_t)(bn*BN + r0 + sr))*K + k0 + sc, &Bs[bb][r0][0]); }
  };

  #pragma unroll
  for (int p=0;p<PREF;p++) stage(p,p);
  asm volatile("s_waitcnt vmcnt(%0)" :: "n"(WAIT) : "memory");
  __builtin_amdgcn_s_barrier();
  __builtin_amdgcn_sched_barrier(0);

  const char* abase = (const char*)&As[0][0][0];
  const char* bbase = (const char*)&Bs[0][0][0];
  for (int kt=0; kt<KT; ++kt) {
    int bb = kt%NBUF;
    if (kt+PREF < KT) stage(kt+PREF, (kt+PREF)%NBUF);
    #pragma unroll
    for (int kk=0;kk<KKN;kk++){
      bf16x8 af[MF], bfr[NF];
      #pragma unroll
      for (int i=0;i<MF;i++){
        int row = wm*(BM/WM)+i*16+li;
        int slot = (kk*4+g) ^ (li & SMASK);
        af[i] = *(const bf16x8*)(abase + (size_t)bb*BM*BK*2 + row*BK*2 + slot*16);
      }
      #pragma unroll
      for (int j=0;j<NF;j++){
        int row = wn*(BN/WN)+j*16+li;
        int slot = (kk*4+g) ^ (li & SMASK);
        bfr[j] = *(const bf16x8*)(bbase + (size_t)bb*BN*BK*2 + row*BK*2 + slot*16);
      }
      __builtin_amdgcn_s_setprio(1);
      #pragma unroll
      for (int i=0;i<MF;i++)
        #pragma unroll
        for (int j=0;j<NF;j++)
          acc[i][j] = __builtin_amdgcn_mfma_f32_16x16x32_bf16(af[i], bfr[j], acc[i][j], 0,0,0);
      __builtin_amdgcn_s_setprio(0);
    }
    if (kt+1 < KT) {
      if (kt+PREF < KT) asm volatile("s_waitcnt vmcnt(%0)" :: "n"(WAIT) : "memory");
      else              asm volatile("s_waitcnt vmcnt(0)" ::: "memory");
      __builtin_amdgcn_s_barrier();
      __builtin_amdgcn_sched_barrier(0);
    }
  }

  #pragma unroll
  for (int i=0;i<MF;i++){
    int row0 = bm*BM + wm*(BM/WM) + i*16 + g*4;
    #pragma unroll
    for (int j=0;j<NF;j++){
      int col = bn*BN + wn*(BN/WN) + j*16 + li;
      if (EPI==0){
        if (col < 1536) {
          float qs = (col < 768) ? LOG2E : 1.0f;   // 768 % 16 == 0: uniform/tile
          #pragma unroll
          for (int r=0;r<4;r++) qk[(size_t)(row0+r)*1536 + col] = (bf16)(acc[i][j][r]*qs);
        } else {
          int cv = col - 1536; int hh = cv>>6, dd = cv&63;
          int b_ = row0>>11,  n0 = row0&2047;
          u16x4 u;
          #pragma unroll
          for (int r=0;r<4;r++){ bf16 bv = (bf16)acc[i][j][r];
            u[r] = __builtin_bit_cast(unsigned short, bv); }
          *reinterpret_cast<u16x4*>(vt + ((size_t)((b_*NH+hh)*HD+dd))*SEQ + n0) = u;
        }
      } else {
        float bb2 = bo[col];
        #pragma unroll
        for (int r=0;r<4;r++){ size_t idx2 = (size_t)(row0+r)*DM + col;
          out[idx2] = acc[i][j][r] + bb2 + xres[idx2]; }
      }
    }
  }
}

// ---------------- flash attention: FROZEN at round-15 form (control) --------
// 256-thr blocks, waves 0-1 kv[0,1024) / 2-3 kv[1024,2048), 32q/wave,
// K single-buffered + V double-buffered, fp32 merge through dead K LDS.
__global__ __launch_bounds__(256) void attn_kernel(
    const bf16* __restrict__ QK, const bf16* __restrict__ Vt,
    bf16* __restrict__ vals)
{
  __shared__ char smem[49408];
  int tid=threadIdx.x, w=tid>>6, la=tid&63;
  int half = w>>1, wl = w&1;
  int id = blockIdx.x;
  int xcd = id & 7, idx = id >> 3;       // 768 = 8 * 96, bijective
  int bh  = xcd*3 + idx/32;              // 3 (b,h) per XCD -> K/V L2-resident
  int qt  = idx & 31;                    // 64-q tiles
  int b = bh/NH, hh = bh%NH;
  int g=la>>4, li=la&15;
  int lr=la>>3;
  int lx=li&7;
  int lcs=((la&7)^lr)*8;           // swizzled source column (elements)
  size_t qrow0=(size_t)b*SEQ + qt*64;
  int kv0 = half*1024;

  bf16x8 qf[2][2];   // [kk][qh]
  #pragma unroll
  for (int qh=0;qh<2;qh++){
    const bf16* qp = QK + (qrow0 + wl*32 + qh*16 + li)*1536 + hh*64;
    qf[0][qh] = *(const bf16x8*)(qp + g*8);
    qf[1][qh] = *(const bf16x8*)(qp + 32 + g*8);
  }

  const bf16* Kbase = QK + (size_t)b*SEQ*1536 + 768 + hh*64;
  const bf16* Vbase = Vt + (size_t)(b*NH+hh)*HD*SEQ;
  char* kreg = smem + half*8192;

  auto stageK = [&](int tt) {
    int j0 = kv0 + tt*64;
    #pragma unroll
    for (int i=0;i<4;i++){ int r0 = wl*32 + i*8;
      gload16(Kbase + (size_t)(j0 + r0 + lr)*1536 + lcs, kreg + r0*128); }
  };
  auto stageV = [&](int tt, int vb) {
    int j0 = kv0 + tt*64;
    char* vreg = smem + 16384 + (half*2+vb)*8192;
    #pragma unroll
    for (int i=0;i<4;i++){ int r0 = wl*32 + i*8;
      gload16(Vbase + (size_t)(r0 + lr)*SEQ + j0 + lcs, vreg + r0*128); }
  };

  stageK(0); stageV(0,0);
  asm volatile("s_waitcnt vmcnt(0)" ::: "memory");
  __builtin_amdgcn_s_barrier();
  __builtin_amdgcn_sched_barrier(0);

  f32x4 o[2][4] = {};        // [qh][df]
  float lp[2][2] = {};       // [qh][chain]

  for (int t=0;t<16;t++){
    f32x4 s[2][4] = {};
    #pragma unroll
    for (int kk=0;kk<2;kk++){
      bf16x8 kf[4];
      #pragma unroll
      for (int nf=0;nf<4;nf++){
        int row = nf*16+li;
        kf[nf] = *(const bf16x8*)(kreg + row*128 + (((kk*4+g)^lx)<<4));
      }
      __builtin_amdgcn_s_setprio(1);
      #pragma unroll
      for (int nf=0;nf<4;nf++){
        s[0][nf] = __builtin_amdgcn_mfma_f32_16x16x32_bf16(kf[nf], qf[kk][0], s[0][nf], 0,0,0);
        s[1][nf] = __builtin_amdgcn_mfma_f32_16x16x32_bf16(kf[nf], qf[kk][1], s[1][nf], 0,0,0);
      }
      __builtin_amdgcn_s_setprio(0);
    }
    if (t+1 < 16) {
      __builtin_amdgcn_s_barrier();
      stageK(t+1);
      stageV(t+1, (t+1)&1);
    }
    bf16x8 pa[2][2];   // [qh][ks]
    #pragma unroll
    for (int qh=0;qh<2;qh++){
      float p[4][4];
      #pragma unroll
      for (int nf=0;nf<4;nf++)
        #pragma unroll
        for (int r=0;r<4;r++){
          p[nf][r] = __builtin_amdgcn_exp2f(s[qh][nf][r]);
          lp[qh][nf&1] += p[nf][r];
        }
      #pragma unroll
      for (int ks=0;ks<2;ks++){
        unsigned int c00,c01,c10,c11;
        asm("v_cvt_pk_bf16_f32 %0, %1, %2" : "=v"(c00) : "v"(p[2*ks  ][0]), "v"(p[2*ks  ][1]));
        asm("v_cvt_pk_bf16_f32 %0, %1, %2" : "=v"(c01) : "v"(p[2*ks  ][2]), "v"(p[2*ks  ][3]));
        asm("v_cvt_pk_bf16_f32 %0, %1, %2" : "=v"(c10) : "v"(p[2*ks+1][0]), "v"(p[2*ks+1][1]));
        asm("v_cvt_pk_bf16_f32 %0, %1, %2" : "=v"(c11) : "v"(p[2*ks+1][2]), "v"(p[2*ks+1][3]));
        asm("v_permlane32_swap_b32 %0, %1" : "+v"(c00), "+v"(c10));
        asm("v_permlane32_swap_b32 %0, %1" : "+v"(c01), "+v"(c11));
        asm("v_permlane16_swap_b32 %0, %1" : "+v"(c00), "+v"(c10));
        asm("v_permlane16_swap_b32 %0, %1" : "+v"(c01), "+v"(c11));
        u32x4v cc = {c00, c01, c10, c11};
        pa[qh][ks] = __builtin_bit_cast(bf16x8, cc);
      }
    }
    const char* vreg = smem + 16384 + (half*2+(t&1))*8192;
    #pragma unroll
    for (int ks=0;ks<2;ks++){
      bf16x8 vb[4];
      #pragma unroll
      for (int df=0;df<4;df++){
        int row = df*16+li;
        vb[df] = *(const bf16x8*)(vreg + row*128 + (((ks*4+g)^lx)<<4));
      }
      __builtin_amdgcn_s_setprio(1);
      #pragma unroll
      for (int qh=0;qh<2;qh++)
        #pragma unroll
        for (int df=0;df<4;df++)
          o[qh][df] = __builtin_amdgcn_mfma_f32_16x16x32_bf16(vb[df], pa[qh][ks], o[qh][df], 0,0,0);
      __builtin_amdgcn_s_setprio(0);
    }
    if (t+1 < 16) {
      asm volatile("s_waitcnt vmcnt(0)" ::: "memory");
      __builtin_amdgcn_s_barrier();
      __builtin_amdgcn_sched_barrier(0);
    }
  }
  float lsum[2];
  #pragma unroll
  for (int qh=0;qh<2;qh++){
    float v = lp[qh][0] + lp[qh][1];
    v += __shfl_xor(v, 16, 64);
    v += __shfl_xor(v, 32, 64);
    lsum[qh] = v;
  }
  __syncthreads();
  float* om  = (float*)smem;                // [64 q][64 d] fp32, slot-swizzled
  float* lmf = (float*)(smem + 49152);      // [64] fp32
  if (half==1){
    #pragma unroll
    for (int qh=0;qh<2;qh++){
      int row = wl*32 + qh*16 + li;
      float* orow = om + row*64;
      #pragma unroll
      for (int df=0;df<4;df++){
        int slot = (df*4 + g) ^ (row & 15);
        *reinterpret_cast<f32x4*>(orow + slot*4) = o[qh][df];
      }
      if (g==0) lmf[row] = lsum[qh];
    }
  }
  __syncthreads();
  if (half==0){
    #pragma unroll
    for (int qh=0;qh<2;qh++){
      int row = wl*32 + qh*16 + li;
      const float* orow = om + row*64;
      float ltot = lsum[qh] + lmf[row];
      float fac = ATT_SCALE / ltot;
      bf16* vrow = vals + (qrow0 + row)*DM + hh*64;
      #pragma unroll
      for (int df=0;df<4;df++){
        int slot = (df*4 + g) ^ (row & 15);
        f32x4 pv = *reinterpret_cast<const f32x4*>(orow + slot*4);
        u16x4 u;
        #pragma unroll
        for (int r=0;r<4;r++){
          bf16 bv = (bf16)((o[qh][df][r] + pv[r]) * fac);
          u[r] = __builtin_bit_cast(unsigned short, bv);
        }
        *reinterpret_cast<u16x4*>(vrow + df*16 + g*4) = u;
      }
    }
  }
}

// ---------------- launch -----------------------------------------------------
extern "C" void kernel_launch(void* const* d_in, const int* in_sizes, int n_in,
                              void* d_out, int out_size, void* d_ws, size_t ws_size,
                              hipStream_t stream)
{
  const float* x     = (const float*)d_in[0];
  const float* Wq    = (const float*)d_in[1];
  const float* Wk    = (const float*)d_in[2];
  const float* Wv    = (const float*)d_in[3];
  const float* Wo    = (const float*)d_in[4];
  const float* bo    = (const float*)d_in[5];
  const float* gamma = (const float*)d_in[6];
  const float* beta  = (const float*)d_in[7];
  float* out = (float*)d_out;
  char* ws = (char*)d_ws;

  bf16* h     = (bf16*)(ws + 0);          // 4096*768*2    = 6291456
  bf16* vals  = (bf16*)(ws + 0);          // alias of h (h dead after GEMM1)
  bf16* Wqkvt = (bf16*)(ws + 6291456);    // 2304*768*2    = 3538944
  bf16* Wot   = (bf16*)(ws + 9830400);    // 768*768*2     = 1179648
  bf16* QKb   = (bf16*)(ws + 11010048);   // 4096*1536*2   = 12582912
  bf16* Vt    = (bf16*)(ws + 23592960);   // 24*64*2048*2  = 6291456
  (void)ws_size; (void)in_sizes; (void)n_in; (void)out_size;

  prep_kernel<<<dim3(6400), dim3(256), 0, stream>>>(
      x, gamma, beta, h, Wq, Wk, Wv, Wo, Wqkvt, Wot);
  // GEMM1: 64x128 tile, 4 waves, BK=32, 3-buffer; 1152 blocks = 4 resident/CU
  gemm_bt<64,128,32,2,2,3,64,18,0><<<dim3(1152), dim3(256), 0, stream>>>(
      h, Wqkvt, DM, QKb, Vt, nullptr, nullptr, nullptr);
  attn_kernel<<<dim3(768), dim3(256), 0, stream>>>(QKb, Vt, vals);
  // GEMM2: 64x64 tile, 4 waves, BK=64, 2-buffer (32KB); 768 blocks = 3/CU all resident
  gemm_bt<64,64,64,2,2,2,64,12,1><<<dim3(768), dim3(256), 0, stream>>>(
      vals, Wot, DM, nullptr, nullptr, out, bo, x);
}

// Round 18
// 95.423 us; speedup vs baseline: 1.0872x; 1.0872x over previous
//
#include <hip/hip_runtime.h>
#include <stdint.h>

typedef __bf16 bf16;
typedef __bf16 bf16x8 __attribute__((ext_vector_type(8)));
typedef float  f32x4  __attribute__((ext_vector_type(4)));
typedef unsigned short u16x4 __attribute__((ext_vector_type(4)));
typedef unsigned int   u32x4v __attribute__((ext_vector_type(4)));

#define SEQ   2048
#define DM    768
#define NH    12
#define HD    64
#define ATT_SCALE 0.125f
#define LOG2E 1.44269504f
#define LN_EPS 1e-5f

// async global->LDS, 16B per lane; LDS dest is wave-uniform base + lane*16
__device__ __forceinline__ void gload16(const void* g, void* l) {
  __builtin_amdgcn_global_load_lds((const __attribute__((address_space(1))) void*)g,
                                   (__attribute__((address_space(3))) void*)l,
                                   16, 0, 0);
}

// ---------------- prep: LN (blocks 0..4095) + weight transpose (4096..6399) -
__global__ __launch_bounds__(256) void prep_kernel(
    const float* __restrict__ x, const float* __restrict__ gamma,
    const float* __restrict__ beta, bf16* __restrict__ h,
    const float* __restrict__ Wq, const float* __restrict__ Wk,
    const float* __restrict__ Wv, const float* __restrict__ Wo,
    bf16* __restrict__ Wqkvt, bf16* __restrict__ Wot)
{
  __shared__ float smem[32*33];
  int bid = blockIdx.x, t = threadIdx.x;
  if (bid < 4096) {
    const float* xr = x + (size_t)bid*DM;
    float v0 = xr[t], v1 = xr[t+256], v2 = xr[t+512];
    float s = v0+v1+v2;
    float q = v0*v0+v1*v1+v2*v2;
    #pragma unroll
    for (int m=32;m>=1;m>>=1){ s += __shfl_xor(s,m,64); q += __shfl_xor(q,m,64); }
    float* rs = smem; float* rq = smem+8;
    int w = t>>6;
    if ((t&63)==0){ rs[w]=s; rq[w]=q; }
    __syncthreads();
    float S = rs[0]+rs[1]+rs[2]+rs[3];
    float Q = rq[0]+rq[1]+rq[2]+rq[3];
    float mean = S*(1.0f/DM);
    float var  = Q*(1.0f/DM) - mean*mean;
    float rstd = rsqrtf(var + LN_EPS);
    bf16* hr = h + (size_t)bid*DM;
    hr[t]     = (bf16)((v0-mean)*rstd*gamma[t]     + beta[t]);
    hr[t+256] = (bf16)((v1-mean)*rstd*gamma[t+256] + beta[t+256]);
    hr[t+512] = (bf16)((v2-mean)*rstd*gamma[t+512] + beta[t+512]);
  } else {
    int tb = bid - 4096;
    int z = tb/576, rem = tb%576;
    int r0 = (rem/24)*32, c0 = (rem%24)*32;
    int tx = t&31, ty = t>>5;   // (32,8)
    float (*tile)[33] = (float(*)[33])smem;
    const float* src = (z==0)?Wq:(z==1)?Wk:(z==2)?Wv:Wo;
    #pragma unroll
    for (int i=ty;i<32;i+=8) tile[i][tx] = src[(size_t)(r0+i)*DM + c0+tx];
    __syncthreads();
    bf16* dst = (z<3) ? (Wqkvt + (size_t)z*DM*DM) : Wot;
    #pragma unroll
    for (int i=ty;i<32;i+=8) dst[(size_t)(c0+i)*DM + r0+tx] = (bf16)tile[tx][i];
  }
}

// ---------------- GEMM: C = A * Bt^T, templated BK + waves, 3-buffer pipeline
// LDS XOR-swizzled: staging pre-swizzles the SOURCE slot by row&SMASK (dest
// stays linear per global_load_lds rules), frag reads XOR the slot back.
// BK=64: 8 slots -> conflict-free; BK=32: 4 slots -> 4-way floor.
// EPI 0: QKV epilogue (Q cols scaled LOG2E; V -> V^T [b][h][d][n])
// EPI 1: out fp32 = acc + bo[col] + x[row][col]
template<int BM, int BN, int BK, int WM, int WN, int EPI>
__global__ __launch_bounds__(WM*WN*64) void gemm_bt(
    const bf16* __restrict__ A, const bf16* __restrict__ Bt, int K,
    bf16* __restrict__ qk, bf16* __restrict__ vt,
    float* __restrict__ out, const float* __restrict__ bo, const float* __restrict__ xres)
{
  constexpr int NW    = WM*WN;            // waves per block
  constexpr int MF    = BM/(WM*16);
  constexpr int NF    = BN/(WN*16);
  constexpr int GL    = (BM+BN)*BK/(512*NW); // gloads per wave per stage
  constexpr int RPI   = 512/BK;           // rows covered per gload16 instr
  constexpr int KKN   = BK/32;            // MFMA k-steps per tile
  constexpr int SLOTS = BK/8;             // 16B slots per row
  constexpr int SMASK = SLOTS-1;
  __shared__ bf16 As[3][BM][BK];
  __shared__ bf16 Bs[3][BN][BK];
  int tid = threadIdx.x, w = tid>>6, la = tid&63;
  int bn = blockIdx.x, bm = blockIdx.y;
  int wm = w / WN, wn = w % WN;
  int g = la>>4, li = la&15;
  int sr = la / SLOTS;                    // staging row within group
  int sc = ((la % SLOTS) ^ (sr & SMASK))*8; // pre-swizzled source col (elems)
  f32x4 acc[MF][NF] = {};
  const int KT = K/BK;

  auto stage = [&](int kt, int bb) {
    int k0 = kt*BK;
    #pragma unroll
    for (int i=0;i<BM/(RPI*NW);i++){ int r0 = (i*NW+w)*RPI;
      gload16(A + ((size_t)(bm*BM + r0 + sr))*K + k0 + sc, &As[bb][r0][0]); }
    #pragma unroll
    for (int i=0;i<BN/(RPI*NW);i++){ int r0 = (i*NW+w)*RPI;
      gload16(Bt + ((size_t)(bn*BN + r0 + sr))*K + k0 + sc, &Bs[bb][r0][0]); }
  };

  stage(0,0); stage(1,1);
  asm volatile("s_waitcnt vmcnt(%0)" :: "n"(GL) : "memory");
  __builtin_amdgcn_s_barrier();
  __builtin_amdgcn_sched_barrier(0);

  const char* abase = (const char*)&As[0][0][0];
  const char* bbase = (const char*)&Bs[0][0][0];
  for (int kt=0; kt<KT; ++kt) {
    int bb = kt%3;
    if (kt+2 < KT) stage(kt+2, (kt+2)%3);
    #pragma unroll
    for (int kk=0;kk<KKN;kk++){
      bf16x8 af[MF], bfr[NF];
      #pragma unroll
      for (int i=0;i<MF;i++){
        int row = wm*(BM/WM)+i*16+li;
        int slot = (kk*4+g) ^ (li & SMASK);
        af[i] = *(const bf16x8*)(abase + (size_t)bb*BM*BK*2 + row*BK*2 + slot*16);
      }
      #pragma unroll
      for (int j=0;j<NF;j++){
        int row = wn*(BN/WN)+j*16+li;
        int slot = (kk*4+g) ^ (li & SMASK);
        bfr[j] = *(const bf16x8*)(bbase + (size_t)bb*BN*BK*2 + row*BK*2 + slot*16);
      }
      __builtin_amdgcn_s_setprio(1);
      #pragma unroll
      for (int i=0;i<MF;i++)
        #pragma unroll
        for (int j=0;j<NF;j++)
          acc[i][j] = __builtin_amdgcn_mfma_f32_16x16x32_bf16(af[i], bfr[j], acc[i][j], 0,0,0);
      __builtin_amdgcn_s_setprio(0);
    }
    if (kt+1 < KT) {
      if (kt+2 < KT) asm volatile("s_waitcnt vmcnt(%0)" :: "n"(GL) : "memory");
      else           asm volatile("s_waitcnt vmcnt(0)" ::: "memory");
      __builtin_amdgcn_s_barrier();
      __builtin_amdgcn_sched_barrier(0);
    }
  }

  #pragma unroll
  for (int i=0;i<MF;i++){
    int row0 = bm*BM + wm*(BM/WM) + i*16 + g*4;
    #pragma unroll
    for (int j=0;j<NF;j++){
      int col = bn*BN + wn*(BN/WN) + j*16 + li;
      if (EPI==0){
        if (col < 1536) {
          float qs = (col < 768) ? LOG2E : 1.0f;   // uniform per j-tile (768%BN==0)
          #pragma unroll
          for (int r=0;r<4;r++) qk[(size_t)(row0+r)*1536 + col] = (bf16)(acc[i][j][r]*qs);
        } else {
          int cv = col - 1536; int hh = cv>>6, dd = cv&63;
          int b_ = row0>>11,  n0 = row0&2047;
          u16x4 u;
          #pragma unroll
          for (int r=0;r<4;r++){ bf16 bv = (bf16)acc[i][j][r];
            u[r] = __builtin_bit_cast(unsigned short, bv); }
          *reinterpret_cast<u16x4*>(vt + ((size_t)((b_*NH+hh)*HD+dd))*SEQ + n0) = u;
        }
      } else {
        float bb2 = bo[col];
        #pragma unroll
        for (int r=0;r<4;r++){ size_t idx = (size_t)(row0+r)*DM + col;
          out[idx] = acc[i][j][r] + bb2 + xres[idx]; }
      }
    }
  }
}

// ---------------- flash attention: FROZEN at round-15 form (control) --------
// 256-thr blocks, waves 0-1 kv[0,1024) / 2-3 kv[1024,2048), 32q/wave,
// K single-buffered + V double-buffered, fp32 merge through dead K LDS.
__global__ __launch_bounds__(256) void attn_kernel(
    const bf16* __restrict__ QK, const bf16* __restrict__ Vt,
    bf16* __restrict__ vals)
{
  __shared__ char smem[49408];
  int tid=threadIdx.x, w=tid>>6, la=tid&63;
  int half = w>>1, wl = w&1;
  int id = blockIdx.x;
  int xcd = id & 7, idx = id >> 3;       // 768 = 8 * 96, bijective
  int bh  = xcd*3 + idx/32;              // 3 (b,h) per XCD -> K/V L2-resident
  int qt  = idx & 31;                    // 64-q tiles
  int b = bh/NH, hh = bh%NH;
  int g=la>>4, li=la&15;
  int lr=la>>3;
  int lx=li&7;
  int lcs=((la&7)^lr)*8;           // swizzled source column (elements)
  size_t qrow0=(size_t)b*SEQ + qt*64;
  int kv0 = half*1024;

  bf16x8 qf[2][2];   // [kk][qh]
  #pragma unroll
  for (int qh=0;qh<2;qh++){
    const bf16* qp = QK + (qrow0 + wl*32 + qh*16 + li)*1536 + hh*64;
    qf[0][qh] = *(const bf16x8*)(qp + g*8);
    qf[1][qh] = *(const bf16x8*)(qp + 32 + g*8);
  }

  const bf16* Kbase = QK + (size_t)b*SEQ*1536 + 768 + hh*64;
  const bf16* Vbase = Vt + (size_t)(b*NH+hh)*HD*SEQ;
  char* kreg = smem + half*8192;

  auto stageK = [&](int tt) {
    int j0 = kv0 + tt*64;
    #pragma unroll
    for (int i=0;i<4;i++){ int r0 = wl*32 + i*8;
      gload16(Kbase + (size_t)(j0 + r0 + lr)*1536 + lcs, kreg + r0*128); }
  };
  auto stageV = [&](int tt, int vb) {
    int j0 = kv0 + tt*64;
    char* vreg = smem + 16384 + (half*2+vb)*8192;
    #pragma unroll
    for (int i=0;i<4;i++){ int r0 = wl*32 + i*8;
      gload16(Vbase + (size_t)(r0 + lr)*SEQ + j0 + lcs, vreg + r0*128); }
  };

  stageK(0); stageV(0,0);
  asm volatile("s_waitcnt vmcnt(0)" ::: "memory");
  __builtin_amdgcn_s_barrier();
  __builtin_amdgcn_sched_barrier(0);

  f32x4 o[2][4] = {};        // [qh][df]
  float lp[2][2] = {};       // [qh][chain]

  for (int t=0;t<16;t++){
    f32x4 s[2][4] = {};
    #pragma unroll
    for (int kk=0;kk<2;kk++){
      bf16x8 kf[4];
      #pragma unroll
      for (int nf=0;nf<4;nf++){
        int row = nf*16+li;
        kf[nf] = *(const bf16x8*)(kreg + row*128 + (((kk*4+g)^lx)<<4));
      }
      __builtin_amdgcn_s_setprio(1);
      #pragma unroll
      for (int nf=0;nf<4;nf++){
        s[0][nf] = __builtin_amdgcn_mfma_f32_16x16x32_bf16(kf[nf], qf[kk][0], s[0][nf], 0,0,0);
        s[1][nf] = __builtin_amdgcn_mfma_f32_16x16x32_bf16(kf[nf], qf[kk][1], s[1][nf], 0,0,0);
      }
      __builtin_amdgcn_s_setprio(0);
    }
    if (t+1 < 16) {
      __builtin_amdgcn_s_barrier();
      stageK(t+1);
      stageV(t+1, (t+1)&1);
    }
    bf16x8 pa[2][2];   // [qh][ks]
    #pragma unroll
    for (int qh=0;qh<2;qh++){
      float p[4][4];
      #pragma unroll
      for (int nf=0;nf<4;nf++)
        #pragma unroll
        for (int r=0;r<4;r++){
          p[nf][r] = __builtin_amdgcn_exp2f(s[qh][nf][r]);
          lp[qh][nf&1] += p[nf][r];
        }
      #pragma unroll
      for (int ks=0;ks<2;ks++){
        unsigned int c00,c01,c10,c11;
        asm("v_cvt_pk_bf16_f32 %0, %1, %2" : "=v"(c00) : "v"(p[2*ks  ][0]), "v"(p[2*ks  ][1]));
        asm("v_cvt_pk_bf16_f32 %0, %1, %2" : "=v"(c01) : "v"(p[2*ks  ][2]), "v"(p[2*ks  ][3]));
        asm("v_cvt_pk_bf16_f32 %0, %1, %2" : "=v"(c10) : "v"(p[2*ks+1][0]), "v"(p[2*ks+1][1]));
        asm("v_cvt_pk_bf16_f32 %0, %1, %2" : "=v"(c11) : "v"(p[2*ks+1][2]), "v"(p[2*ks+1][3]));
        asm("v_permlane32_swap_b32 %0, %1" : "+v"(c00), "+v"(c10));
        asm("v_permlane32_swap_b32 %0, %1" : "+v"(c01), "+v"(c11));
        asm("v_permlane16_swap_b32 %0, %1" : "+v"(c00), "+v"(c10));
        asm("v_permlane16_swap_b32 %0, %1" : "+v"(c01), "+v"(c11));
        u32x4v cc = {c00, c01, c10, c11};
        pa[qh][ks] = __builtin_bit_cast(bf16x8, cc);
      }
    }
    const char* vreg = smem + 16384 + (half*2+(t&1))*8192;
    #pragma unroll
    for (int ks=0;ks<2;ks++){
      bf16x8 vb[4];
      #pragma unroll
      for (int df=0;df<4;df++){
        int row = df*16+li;
        vb[df] = *(const bf16x8*)(vreg + row*128 + (((ks*4+g)^lx)<<4));
      }
      __builtin_amdgcn_s_setprio(1);
      #pragma unroll
      for (int qh=0;qh<2;qh++)
        #pragma unroll
        for (int df=0;df<4;df++)
          o[qh][df] = __builtin_amdgcn_mfma_f32_16x16x32_bf16(vb[df], pa[qh][ks], o[qh][df], 0,0,0);
      __builtin_amdgcn_s_setprio(0);
    }
    if (t+1 < 16) {
      asm volatile("s_waitcnt vmcnt(0)" ::: "memory");
      __builtin_amdgcn_s_barrier();
      __builtin_amdgcn_sched_barrier(0);
    }
  }
  float lsum[2];
  #pragma unroll
  for (int qh=0;qh<2;qh++){
    float v = lp[qh][0] + lp[qh][1];
    v += __shfl_xor(v, 16, 64);
    v += __shfl_xor(v, 32, 64);
    lsum[qh] = v;
  }
  __syncthreads();
  float* om  = (float*)smem;                // [64 q][64 d] fp32, slot-swizzled
  float* lmf = (float*)(smem + 49152);      // [64] fp32
  if (half==1){
    #pragma unroll
    for (int qh=0;qh<2;qh++){
      int row = wl*32 + qh*16 + li;
      float* orow = om + row*64;
      #pragma unroll
      for (int df=0;df<4;df++){
        int slot = (df*4 + g) ^ (row & 15);
        *reinterpret_cast<f32x4*>(orow + slot*4) = o[qh][df];
      }
      if (g==0) lmf[row] = lsum[qh];
    }
  }
  __syncthreads();
  if (half==0){
    #pragma unroll
    for (int qh=0;qh<2;qh++){
      int row = wl*32 + qh*16 + li;
      const float* orow = om + row*64;
      float ltot = lsum[qh] + lmf[row];
      float fac = ATT_SCALE / ltot;
      bf16* vrow = vals + (qrow0 + row)*DM + hh*64;
      #pragma unroll
      for (int df=0;df<4;df++){
        int slot = (df*4 + g) ^ (row & 15);
        f32x4 pv = *reinterpret_cast<const f32x4*>(orow + slot*4);
        u16x4 u;
        #pragma unroll
        for (int r=0;r<4;r++){
          bf16 bv = (bf16)((o[qh][df][r] + pv[r]) * fac);
          u[r] = __builtin_bit_cast(unsigned short, bv);
        }
        *reinterpret_cast<u16x4*>(vrow + df*16 + g*4) = u;
      }
    }
  }
}

// ---------------- launch -----------------------------------------------------
extern "C" void kernel_launch(void* const* d_in, const int* in_sizes, int n_in,
                              void* d_out, int out_size, void* d_ws, size_t ws_size,
                              hipStream_t stream)
{
  const float* x     = (const float*)d_in[0];
  const float* Wq    = (const float*)d_in[1];
  const float* Wk    = (const float*)d_in[2];
  const float* Wv    = (const float*)d_in[3];
  const float* Wo    = (const float*)d_in[4];
  const float* bo    = (const float*)d_in[5];
  const float* gamma = (const float*)d_in[6];
  const float* beta  = (const float*)d_in[7];
  float* out = (float*)d_out;
  char* ws = (char*)d_ws;

  bf16* h     = (bf16*)(ws + 0);          // 4096*768*2    = 6291456
  bf16* vals  = (bf16*)(ws + 0);          // alias of h (h dead after GEMM1)
  bf16* Wqkvt = (bf16*)(ws + 6291456);    // 2304*768*2    = 3538944
  bf16* Wot   = (bf16*)(ws + 9830400);    // 768*768*2     = 1179648
  bf16* QKb   = (bf16*)(ws + 11010048);   // 4096*1536*2   = 12582912
  bf16* Vt    = (bf16*)(ws + 23592960);   // 24*64*2048*2  = 6291456
  (void)ws_size; (void)in_sizes; (void)n_in; (void)out_size;

  prep_kernel<<<dim3(6400), dim3(256), 0, stream>>>(
      x, gamma, beta, h, Wq, Wk, Wv, Wo, Wqkvt, Wot);
  gemm_bt<128,128,32,2,4,0><<<dim3(18,32), dim3(512), 0, stream>>>(
      h, Wqkvt, DM, QKb, Vt, nullptr, nullptr, nullptr);
  attn_kernel<<<dim3(768), dim3(256), 0, stream>>>(QKb, Vt, vals);
  gemm_bt<64,64,64,2,2,1><<<dim3(12,64), dim3(256), 0, stream>>>(
      vals, Wot, DM, nullptr, nullptr, out, bo, x);
}